// Round 2
// baseline (1223.334 us; speedup 1.0000x reference)
//
#include <hip/hip_runtime.h>
#include <math.h>

#define NN 50000
#define NE 800000
#define FIN 128
#define HEADS 4
#define HID 32
#define D1 128
#define NCLS 16
#define NEG 0.2f
#define NINF (-3.402823466e38f)

// ---------------- CSR build ----------------
__global__ void k_count(const int* __restrict__ dst, int* __restrict__ counts) {
  int j = blockIdx.x * 256 + threadIdx.x;
  if (j < NE) atomicAdd(&counts[dst[j]], 1);
}

__global__ void k_scan(const int* __restrict__ counts, int* __restrict__ starts,
                       int* __restrict__ cursor) {
  __shared__ int sums[1024];
  int tid = threadIdx.x;
  const int CH = (NN + 1023) / 1024;
  int base = tid * CH;
  int s = 0;
  for (int i = 0; i < CH; i++) { int idx = base + i; if (idx < NN) s += counts[idx]; }
  sums[tid] = s;
  __syncthreads();
  for (int off = 1; off < 1024; off <<= 1) {
    int v = (tid >= off) ? sums[tid - off] : 0;
    __syncthreads();
    sums[tid] += v;
    __syncthreads();
  }
  int run = (tid == 0) ? 0 : sums[tid - 1];
  for (int i = 0; i < CH; i++) {
    int idx = base + i;
    if (idx < NN) { starts[idx] = run; cursor[idx] = run; run += counts[idx]; }
  }
}

__global__ void k_scatter(const int* __restrict__ src, const int* __restrict__ dst,
                          int* __restrict__ cursor, int* __restrict__ eperm,
                          int* __restrict__ sperm) {
  int j = blockIdx.x * 256 + threadIdx.x;
  if (j < NE) {
    int p = atomicAdd(&cursor[dst[j]], 1);
    eperm[p] = j;
    sperm[p] = src[j];
  }
}

// ---------------- fp32 tiled GEMM ----------------
// ACT: 0=none, 1=elu
template <int BM, int BN, int BK, int TM, int TN, int ACT>
__global__ __launch_bounds__(256) void k_gemm(const float* __restrict__ A,
                                              const float* __restrict__ B,
                                              const float* __restrict__ bias,
                                              float* __restrict__ C, int M, int N, int K) {
  constexpr int NT = (BM / TM) * (BN / TN);
  static_assert(NT == 256, "block must be 256 threads");
  __shared__ float As[BK][BM + 4];
  __shared__ float Bs[BK][BN];
  int tid = threadIdx.x;
  int bm = blockIdx.y * BM, bn = blockIdx.x * BN;
  constexpr int TX = BN / TN;
  int tn = (tid % TX) * TN;
  int tm = (tid / TX) * TM;
  float acc[TM][TN];
#pragma unroll
  for (int i = 0; i < TM; i++)
#pragma unroll
    for (int j = 0; j < TN; j++) acc[i][j] = 0.f;

  for (int k0 = 0; k0 < K; k0 += BK) {
    constexpr int AV = BM * BK / 4;
    for (int i = tid; i < AV; i += NT) {
      int r = i / (BK / 4);
      int c4 = (i % (BK / 4)) * 4;
      float4 v = make_float4(0.f, 0.f, 0.f, 0.f);
      int gr = bm + r;
      if (gr < M) v = *(const float4*)(A + (size_t)gr * K + k0 + c4);
      As[c4 + 0][r] = v.x; As[c4 + 1][r] = v.y; As[c4 + 2][r] = v.z; As[c4 + 3][r] = v.w;
    }
    constexpr int BV = BK * BN / 4;
    for (int i = tid; i < BV; i += NT) {
      int r = i / (BN / 4), c4 = (i % (BN / 4)) * 4;
      float4 v = *(const float4*)(B + (size_t)(k0 + r) * N + bn + c4);
      Bs[r][c4 + 0] = v.x; Bs[r][c4 + 1] = v.y; Bs[r][c4 + 2] = v.z; Bs[r][c4 + 3] = v.w;
    }
    __syncthreads();
#pragma unroll
    for (int kk = 0; kk < BK; kk++) {
      float ra[TM], rb[TN];
#pragma unroll
      for (int i = 0; i < TM; i++) ra[i] = As[kk][tm + i];
#pragma unroll
      for (int j = 0; j < TN; j++) rb[j] = Bs[kk][tn + j];
#pragma unroll
      for (int i = 0; i < TM; i++)
#pragma unroll
        for (int j = 0; j < TN; j++) acc[i][j] += ra[i] * rb[j];
    }
    __syncthreads();
  }
#pragma unroll
  for (int i = 0; i < TM; i++) {
    int gr = bm + tm + i;
    if (gr >= M) continue;
#pragma unroll
    for (int j = 0; j < TN; j++) {
      float v = acc[i][j];
      if (bias) v += bias[bn + tn + j];
      if (ACT == 1) v = v > 0.f ? v : expm1f(v);
      C[(size_t)gr * N + bn + tn + j] = v;
    }
  }
}

// ---------------- fused scores + top-k + dual softmax + aggregation ----------------
// One block (256 threads) per dst node. Edges of the dst segment are cached in
// LDS (xl rows) during scoring so aggregation needs no second global gather.
// CAP=64: P(Poisson(16) deg > 64) ~ 2e-18 over 50k nodes -> unreachable.
// MODE 0 (layer1): out0 = elu(agg + b), out1 = noise + b
// MODE 1 (layer2): out0 = log_softmax(agg + b), out1 = log_softmax(noise + b)
template <int H, int C, int MODE>
__global__ __launch_bounds__(256) void k_fused(
    const float* __restrict__ xl, const float* __restrict__ xr,
    const float* __restrict__ att, const int* __restrict__ sperm,
    const int* __restrict__ eperm, const int* __restrict__ starts,
    const int* __restrict__ counts, const int* __restrict__ kptr,
    const float* __restrict__ bias, float* __restrict__ out0,
    float* __restrict__ out1) {
  constexpr int ROW = H * C;        // 128 or 16
  constexpr int EPB = 256 / ROW;    // edges per scoring iter: 2 or 16
  constexpr int CAP = 64;
  __shared__ float cache[CAP][ROW];   // xl[src] rows
  __shared__ float xrs[ROW];
  __shared__ float sc[CAP][H + 1];    // scores (padded stride)
  __shared__ float wgt[CAP][H + 1];   // softmax weights, sign-coded
  __shared__ int ids[CAP];            // original edge ids (tie-break)
  __shared__ int ss[CAP];             // src node per edge
  __shared__ float po[EPB][ROW], pn[EPB][ROW];

  int d = blockIdx.x;
  int tid = threadIdx.x;
  int st = starts[d];
  int deg = counts[d];
  if (deg > CAP) deg = CAP;  // unreachable safeguard
  int k = kptr[0];

  if (tid < ROW) xrs[tid] = xr[(size_t)d * ROW + tid];
  if (tid < deg) { ids[tid] = eperm[st + tid]; ss[tid] = sperm[st + tid]; }
  __syncthreads();

  int e = tid / ROW;       // edge-group within block
  int t = tid - e * ROW;   // channel = h*C + c
  int h = t / C;
  float attv = att[t];

  // ---- scoring + xl caching ----
  for (int q = e; q < deg; q += EPB) {
    float xv = xl[(size_t)ss[q] * ROW + t];
    float v = xv + xrs[t];
    float lr = v > 0.f ? v : NEG * v;
    float p = lr * attv;
#pragma unroll
    for (int o = C / 2; o; o >>= 1) p += __shfl_xor(p, o, 64);
    cache[q][t] = xv;
    if ((t & (C - 1)) == 0) sc[q][h] = p;
  }
  __syncthreads();

  // ---- per-head top-k + dual softmax (one wave per head) ----
  int wave = tid >> 6, lane = tid & 63;
  if (wave < H) {
    int hh = wave;
    float v = lane < deg ? sc[lane][hh] : NINF;
    int id = lane < deg ? ids[lane] : 0x7fffffff;
    float mk = v;
#pragma unroll
    for (int o = 32; o; o >>= 1) mk = fmaxf(mk, __shfl_xor(mk, o, 64));
    int kk = k < deg ? k : deg;
    bool kept = false;
    float curv = v; int curi = id;
    for (int it = 0; it < kk; it++) {
      float bv = curv; int bi = curi;
#pragma unroll
      for (int o = 32; o; o >>= 1) {
        float ov = __shfl_xor(bv, o, 64);
        int oi = __shfl_xor(bi, o, 64);
        if (ov > bv || (ov == bv && oi < bi)) { bv = ov; bi = oi; }
      }
      if (curv == bv && curi == bi) { kept = true; curv = NINF; curi = 0x7fffffff; }
    }
    float mn = curv;  // max over noise set
#pragma unroll
    for (int o = 32; o; o >>= 1) mn = fmaxf(mn, __shfl_xor(mn, o, 64));
    float ek = kept ? __expf(v - mk) : 0.f;
    float en = (!kept && lane < deg) ? __expf(v - mn) : 0.f;
    float sk = ek, sn = en;
#pragma unroll
    for (int o = 32; o; o >>= 1) {
      sk += __shfl_xor(sk, o, 64);
      sn += __shfl_xor(sn, o, 64);
    }
    if (lane < deg)
      wgt[lane][hh] = kept ? ek / (sk + 1e-16f) : -(en / (sn + 1e-16f));
  }
  __syncthreads();

  // ---- aggregation from LDS ----
  float ao = 0.f, an = 0.f;
  for (int q = e; q < deg; q += EPB) {
    float w = wgt[q][h];
    float xv = cache[q][t];
    if (w > 0.f) ao += w * xv; else an -= w * xv;
  }
  po[e][t] = ao; pn[e][t] = an;
  __syncthreads();

  if (tid < ROW) {
    float so = 0.f, sn2 = 0.f;
#pragma unroll
    for (int g = 0; g < EPB; g++) { so += po[g][tid]; sn2 += pn[g][tid]; }
    float b = bias[tid];
    float vo = so + b, vn = sn2 + b;
    if (MODE == 0) {
      out0[(size_t)d * ROW + tid] = vo > 0.f ? vo : expm1f(vo);
      out1[(size_t)d * ROW + tid] = vn;
    } else {
      // fused log_softmax over ROW=16 lanes (all in wave 0, aligned)
      float mo = vo, mnv = vn;
#pragma unroll
      for (int o = ROW / 2; o; o >>= 1) {
        mo = fmaxf(mo, __shfl_xor(mo, o, 64));
        mnv = fmaxf(mnv, __shfl_xor(mnv, o, 64));
      }
      float eo = __expf(vo - mo), en2 = __expf(vn - mnv);
#pragma unroll
      for (int o = ROW / 2; o; o >>= 1) {
        eo += __shfl_xor(eo, o, 64);
        en2 += __shfl_xor(en2, o, 64);
      }
      out0[(size_t)d * ROW + tid] = vo - (mo + logf(eo));
      out1[(size_t)d * ROW + tid] = vn - (mnv + logf(en2));
    }
  }
}

// ---------------- row log_softmax over 16 (n1 only) ----------------
__global__ void k_lsm(const float* __restrict__ in, float* __restrict__ out) {
  int r = blockIdx.x * 256 + threadIdx.x;
  if (r >= NN) return;
  const float4* p = (const float4*)(in + (size_t)r * NCLS);
  float4 a = p[0], b = p[1], c = p[2], d4 = p[3];
  float vals[16] = {a.x, a.y, a.z, a.w, b.x, b.y, b.z, b.w,
                    c.x, c.y, c.z, c.w, d4.x, d4.y, d4.z, d4.w};
  float m = vals[0];
#pragma unroll
  for (int i = 1; i < 16; i++) m = fmaxf(m, vals[i]);
  float s = 0.f;
#pragma unroll
  for (int i = 0; i < 16; i++) s += expf(vals[i] - m);
  float l = m + logf(s);
  float* op = out + (size_t)r * NCLS;
#pragma unroll
  for (int i = 0; i < 16; i++) op[i] = vals[i] - l;
}

extern "C" void kernel_launch(void* const* d_in, const int* in_sizes, int n_in,
                              void* d_out, int out_size, void* d_ws, size_t ws_size,
                              hipStream_t stream) {
  (void)in_sizes; (void)n_in; (void)out_size; (void)ws_size;
  const float* x    = (const float*)d_in[0];
  const int*   ei   = (const int*)d_in[1];
  const int*   kptr = (const int*)d_in[2];
  const float* Wl1  = (const float*)d_in[3];
  const float* Wr1  = (const float*)d_in[4];
  const float* att1 = (const float*)d_in[5];
  const float* b1   = (const float*)d_in[6];
  const float* Wl2  = (const float*)d_in[7];
  const float* Wr2  = (const float*)d_in[8];
  const float* att2 = (const float*)d_in[9];
  const float* b2   = (const float*)d_in[10];
  const float* l1w  = (const float*)d_in[11];
  const float* l1b  = (const float*)d_in[12];
  const float* l2w  = (const float*)d_in[13];
  const float* l2b  = (const float*)d_in[14];
  const int* srcv = ei;
  const int* dstv = ei + NE;

  char* wp = (char*)d_ws;
  auto alloc = [&](size_t n) { char* p = wp; wp += (n + 255) & ~(size_t)255; return p; };
  float* xl1    = (float*)alloc((size_t)NN * D1 * 4);  // xl1
  float* bufB   = (float*)alloc((size_t)NN * D1 * 4);  // xr1 -> h (in-place per-row)
  float* noise1 = (float*)alloc((size_t)NN * D1 * 4);  // noise1 -> n1
  float* t1     = (float*)alloc((size_t)NN * D1 * 4);  // mlp hidden -> xl2/xr2
  int* counts = (int*)alloc((size_t)NN * 4);
  int* starts = (int*)alloc((size_t)NN * 4);
  int* cursor = (int*)alloc((size_t)NN * 4);
  int* eperm  = (int*)alloc((size_t)NE * 4);
  int* sperm  = (int*)alloc((size_t)NE * 4);

  // CSR build (by dst)
  hipMemsetAsync(counts, 0, (size_t)NN * 4, stream);
  k_count<<<(NE + 255) / 256, 256, 0, stream>>>(dstv, counts);
  k_scan<<<1, 1024, 0, stream>>>(counts, starts, cursor);
  k_scatter<<<(NE + 255) / 256, 256, 0, stream>>>(srcv, dstv, cursor, eperm, sperm);

  // Layer 1 node transforms
  dim3 gbig(D1 / 64, (NN + 63) / 64);
  k_gemm<64, 64, 32, 4, 4, 0><<<gbig, 256, 0, stream>>>(x, Wl1, nullptr, xl1, NN, D1, FIN);
  k_gemm<64, 64, 32, 4, 4, 0><<<gbig, 256, 0, stream>>>(x, Wr1, nullptr, bufB, NN, D1, FIN);

  // Layer 1 fused edge pipeline: bufB row d is read (xr) before written (h)
  k_fused<HEADS, HID, 0><<<NN, 256, 0, stream>>>(xl1, bufB, att1, sperm, eperm,
                                                 starts, counts, kptr, b1, bufB, noise1);

  // MLP on noise1
  k_gemm<64, 64, 32, 4, 4, 1><<<gbig, 256, 0, stream>>>(noise1, l1w, l1b, t1, NN, 128, 128);
  float* n1v = noise1;
  dim3 gsm(1, (NN + 127) / 128);
  k_gemm<128, 16, 32, 4, 2, 0><<<gsm, 256, 0, stream>>>(t1, l2w, l2b, n1v, NN, NCLS, 128);

  // Layer 2 node transforms (t1 free after lin2)
  float* xl2 = t1;
  float* xr2 = t1 + (size_t)NN * NCLS;
  k_gemm<128, 16, 32, 4, 2, 0><<<gsm, 256, 0, stream>>>(bufB, Wl2, nullptr, xl2, NN, NCLS, D1);
  k_gemm<128, 16, 32, 4, 2, 0><<<gsm, 256, 0, stream>>>(bufB, Wr2, nullptr, xr2, NN, NCLS, D1);

  // Layer 2 fused edge pipeline (+log_softmax epilogue) -> final outputs
  float* o = (float*)d_out;
  k_fused<1, NCLS, 1><<<NN, 256, 0, stream>>>(xl2, xr2, att2, sperm, eperm, starts,
                                              counts, kptr, b2, o,
                                              o + (size_t)2 * NN * NCLS);

  // n1 log_softmax
  k_lsm<<<(NN + 255) / 256, 256, 0, stream>>>(n1v, o + (size_t)NN * NCLS);
}

// Round 3
// 632.482 us; speedup vs baseline: 1.9342x; 1.9342x over previous
//
#include <hip/hip_runtime.h>
#include <math.h>

#define NN 50000
#define NE 800000
#define FIN 128
#define HEADS 4
#define HID 32
#define D1 128
#define NCLS 16
#define NEG 0.2f
#define NINF (-3.402823466e38f)
#define CAP 64

// ---------------- CSR build ----------------
__global__ void k_count(const int* __restrict__ dst, int* __restrict__ counts) {
  int j = blockIdx.x * 256 + threadIdx.x;
  if (j < NE) atomicAdd(&counts[dst[j]], 1);
}

__global__ void k_scan(const int* __restrict__ counts, int* __restrict__ starts,
                       int* __restrict__ cursor) {
  __shared__ int sums[1024];
  int tid = threadIdx.x;
  const int CH = (NN + 1023) / 1024;
  int base = tid * CH;
  int s = 0;
  for (int i = 0; i < CH; i++) { int idx = base + i; if (idx < NN) s += counts[idx]; }
  sums[tid] = s;
  __syncthreads();
  for (int off = 1; off < 1024; off <<= 1) {
    int v = (tid >= off) ? sums[tid - off] : 0;
    __syncthreads();
    sums[tid] += v;
    __syncthreads();
  }
  int run = (tid == 0) ? 0 : sums[tid - 1];
  for (int i = 0; i < CH; i++) {
    int idx = base + i;
    if (idx < NN) { starts[idx] = run; cursor[idx] = run; run += counts[idx]; }
  }
}

__global__ void k_scatter(const int* __restrict__ src, const int* __restrict__ dst,
                          int* __restrict__ cursor, int* __restrict__ eperm,
                          int* __restrict__ sperm) {
  int j = blockIdx.x * 256 + threadIdx.x;
  if (j < NE) {
    int p = atomicAdd(&cursor[dst[j]], 1);
    eperm[p] = j;
    sperm[p] = src[j];
  }
}

// ---------------- fp32 tiled GEMM ----------------
template <int BM, int BN, int BK, int TM, int TN, int ACT>
__global__ __launch_bounds__(256) void k_gemm(const float* __restrict__ A,
                                              const float* __restrict__ B,
                                              const float* __restrict__ bias,
                                              float* __restrict__ C, int M, int N, int K) {
  constexpr int NT = (BM / TM) * (BN / TN);
  static_assert(NT == 256, "block must be 256 threads");
  __shared__ float As[BK][BM + 4];
  __shared__ float Bs[BK][BN];
  int tid = threadIdx.x;
  int bm = blockIdx.y * BM, bn = blockIdx.x * BN;
  constexpr int TX = BN / TN;
  int tn = (tid % TX) * TN;
  int tm = (tid / TX) * TM;
  float acc[TM][TN];
#pragma unroll
  for (int i = 0; i < TM; i++)
#pragma unroll
    for (int j = 0; j < TN; j++) acc[i][j] = 0.f;

  for (int k0 = 0; k0 < K; k0 += BK) {
    constexpr int AV = BM * BK / 4;
    for (int i = tid; i < AV; i += NT) {
      int r = i / (BK / 4);
      int c4 = (i % (BK / 4)) * 4;
      float4 v = make_float4(0.f, 0.f, 0.f, 0.f);
      int gr = bm + r;
      if (gr < M) v = *(const float4*)(A + (size_t)gr * K + k0 + c4);
      As[c4 + 0][r] = v.x; As[c4 + 1][r] = v.y; As[c4 + 2][r] = v.z; As[c4 + 3][r] = v.w;
    }
    constexpr int BV = BK * BN / 4;
    for (int i = tid; i < BV; i += NT) {
      int r = i / (BN / 4), c4 = (i % (BN / 4)) * 4;
      float4 v = *(const float4*)(B + (size_t)(k0 + r) * N + bn + c4);
      Bs[r][c4 + 0] = v.x; Bs[r][c4 + 1] = v.y; Bs[r][c4 + 2] = v.z; Bs[r][c4 + 3] = v.w;
    }
    __syncthreads();
#pragma unroll
    for (int kk = 0; kk < BK; kk++) {
      float ra[TM], rb[TN];
#pragma unroll
      for (int i = 0; i < TM; i++) ra[i] = As[kk][tm + i];
#pragma unroll
      for (int j = 0; j < TN; j++) rb[j] = Bs[kk][tn + j];
#pragma unroll
      for (int i = 0; i < TM; i++)
#pragma unroll
        for (int j = 0; j < TN; j++) acc[i][j] += ra[i] * rb[j];
    }
    __syncthreads();
  }
#pragma unroll
  for (int i = 0; i < TM; i++) {
    int gr = bm + tm + i;
    if (gr >= M) continue;
#pragma unroll
    for (int j = 0; j < TN; j++) {
      float v = acc[i][j];
      if (bias) v += bias[bn + tn + j];
      if (ACT == 1) v = v > 0.f ? v : expm1f(v);
      C[(size_t)gr * N + bn + tn + j] = v;
    }
  }
}

__device__ __forceinline__ bool lex_gt(float av, int ai, float bv, int bi) {
  return (av > bv) || (av == bv && ai < bi);
}

// ---------------- layer-1 fused: wave per dst, 4 dst per block ----------------
// scores + top-k(rank) + dual softmax + aggregation. No __syncthreads; all
// cross-lane comms are intra-wave. LDS holds only per-wave scores (4KB/block).
__global__ __launch_bounds__(256) void k_fused1(
    const float* __restrict__ xl, const float* __restrict__ xr,
    const float* __restrict__ att, const int* __restrict__ sperm,
    const int* __restrict__ eperm, const int* __restrict__ starts,
    const int* __restrict__ counts, const int* __restrict__ kptr,
    const float* __restrict__ bias, float* __restrict__ hout,
    float* __restrict__ nout) {
  __shared__ float sc[4][CAP][4];  // [wave][edge][head], wave-private
  int w = threadIdx.x >> 6;
  int l = threadIdx.x & 63;
  int d = blockIdx.x * 4 + w;
  if (d >= NN) return;  // wave-uniform
  int st = starts[d];
  int deg = counts[d];
  if (deg > CAP) deg = CAP;
  int k = kptr[0];

  int srcreg = 0, idreg = 0x7fffffff;
  if (l < deg) { srcreg = sperm[st + l]; idreg = eperm[st + l]; }

  int h2 = l >> 5, li = l & 31;       // half-wave: row selector / channel group
  int headq = li >> 3;                // head covered by this lane's 4 channels
  float4 xrv = *(const float4*)(xr + (size_t)d * D1 + 4 * li);
  float4 attv = *(const float4*)(att + 4 * li);
  float4 b1v = *(const float4*)(bias + 4 * li);

  // ---- scoring: 4 rows in flight per wave ----
  for (int q = 0; q < deg; q += 4) {
    int r0 = q + h2, r1 = q + 2 + h2;
    int s0 = __shfl(srcreg, r0), s1 = __shfl(srcreg, r1);
    bool v0 = r0 < deg, v1 = r1 < deg;
    float4 x0 = make_float4(0.f, 0.f, 0.f, 0.f), x1 = x0;
    if (v0) x0 = *(const float4*)(xl + (size_t)s0 * D1 + 4 * li);
    if (v1) x1 = *(const float4*)(xl + (size_t)s1 * D1 + 4 * li);
    float a0, a1, p0 = 0.f, p1 = 0.f;
    a0 = x0.x + xrv.x; p0 += (a0 > 0.f ? a0 : NEG * a0) * attv.x;
    a0 = x0.y + xrv.y; p0 += (a0 > 0.f ? a0 : NEG * a0) * attv.y;
    a0 = x0.z + xrv.z; p0 += (a0 > 0.f ? a0 : NEG * a0) * attv.z;
    a0 = x0.w + xrv.w; p0 += (a0 > 0.f ? a0 : NEG * a0) * attv.w;
    a1 = x1.x + xrv.x; p1 += (a1 > 0.f ? a1 : NEG * a1) * attv.x;
    a1 = x1.y + xrv.y; p1 += (a1 > 0.f ? a1 : NEG * a1) * attv.y;
    a1 = x1.z + xrv.z; p1 += (a1 > 0.f ? a1 : NEG * a1) * attv.z;
    a1 = x1.w + xrv.w; p1 += (a1 > 0.f ? a1 : NEG * a1) * attv.w;
#pragma unroll
    for (int o = 1; o <= 4; o <<= 1) {  // reduce 8 lanes (32 ch) per head
      p0 += __shfl_xor(p0, o, 64);
      p1 += __shfl_xor(p1, o, 64);
    }
    if ((li & 7) == 0) {
      if (v0) sc[w][r0][headq] = p0;
      if (v1) sc[w][r1][headq] = p1;
    }
  }

  // ---- top-k + dual softmax: lane = head*16 + i, 4 slots each ----
  int hh = l >> 4, ii = l & 15;
  float sv[4]; int si[4]; int rank[4]; bool val[4];
#pragma unroll
  for (int j = 0; j < 4; j++) {
    int q = j * 16 + ii;
    val[j] = q < deg;
    sv[j] = val[j] ? sc[w][q][hh] : NINF;
    int bid = __shfl(idreg, q);
    si[j] = val[j] ? bid : 0x7fffffff;
    rank[j] = 0;
  }
#pragma unroll
  for (int ch = 0; ch < 4; ch++) {
    if (ch * 16 >= deg) break;
#pragma unroll
    for (int pp = 0; pp < 16; pp++) {
      int p = ch * 16 + pp;
      float bv = __shfl(sv[ch], hh * 16 + pp);
      int bi = __shfl(si[ch], hh * 16 + pp);
      if (p < deg) {
#pragma unroll
        for (int j = 0; j < 4; j++) rank[j] += lex_gt(bv, bi, sv[j], si[j]);
      }
    }
  }
  bool kept[4];
#pragma unroll
  for (int j = 0; j < 4; j++) kept[j] = val[j] && (rank[j] < k);
  float mk = fmaxf(fmaxf(sv[0], sv[1]), fmaxf(sv[2], sv[3]));
  float mn = NINF;
#pragma unroll
  for (int j = 0; j < 4; j++) mn = fmaxf(mn, kept[j] ? NINF : sv[j]);
#pragma unroll
  for (int o = 1; o <= 8; o <<= 1) {  // reduce within 16-lane head group
    mk = fmaxf(mk, __shfl_xor(mk, o, 64));
    mn = fmaxf(mn, __shfl_xor(mn, o, 64));
  }
  float ek[4], en[4], sk = 0.f, sn = 0.f;
#pragma unroll
  for (int j = 0; j < 4; j++) {
    ek[j] = kept[j] ? __expf(sv[j] - mk) : 0.f;
    en[j] = (val[j] && !kept[j]) ? __expf(sv[j] - mn) : 0.f;
    sk += ek[j]; sn += en[j];
  }
#pragma unroll
  for (int o = 1; o <= 8; o <<= 1) {
    sk += __shfl_xor(sk, o, 64);
    sn += __shfl_xor(sn, o, 64);
  }
  float ik = 1.f / (sk + 1e-16f), inn = 1.f / (sn + 1e-16f);
#pragma unroll
  for (int j = 0; j < 4; j++) {
    if (val[j]) sc[w][j * 16 + ii][hh] = kept[j] ? ek[j] * ik : -(en[j] * inn);
  }

  // ---- aggregation (reload xl rows: L1/L2-hot from scoring) ----
  float4 ao = make_float4(0.f, 0.f, 0.f, 0.f), an = ao;
  for (int q = 0; q < deg; q += 4) {
    int r0 = q + h2, r1 = q + 2 + h2;
    int s0 = __shfl(srcreg, r0), s1 = __shfl(srcreg, r1);
    if (r0 < deg) {
      float wv = sc[w][r0][headq];
      float4 xv = *(const float4*)(xl + (size_t)s0 * D1 + 4 * li);
      float s = wv > 0.f ? wv : -wv;
      if (wv > 0.f) { ao.x += s * xv.x; ao.y += s * xv.y; ao.z += s * xv.z; ao.w += s * xv.w; }
      else          { an.x += s * xv.x; an.y += s * xv.y; an.z += s * xv.z; an.w += s * xv.w; }
    }
    if (r1 < deg) {
      float wv = sc[w][r1][headq];
      float4 xv = *(const float4*)(xl + (size_t)s1 * D1 + 4 * li);
      float s = wv > 0.f ? wv : -wv;
      if (wv > 0.f) { ao.x += s * xv.x; ao.y += s * xv.y; ao.z += s * xv.z; ao.w += s * xv.w; }
      else          { an.x += s * xv.x; an.y += s * xv.y; an.z += s * xv.z; an.w += s * xv.w; }
    }
  }
  ao.x += __shfl_xor(ao.x, 32, 64); ao.y += __shfl_xor(ao.y, 32, 64);
  ao.z += __shfl_xor(ao.z, 32, 64); ao.w += __shfl_xor(ao.w, 32, 64);
  an.x += __shfl_xor(an.x, 32, 64); an.y += __shfl_xor(an.y, 32, 64);
  an.z += __shfl_xor(an.z, 32, 64); an.w += __shfl_xor(an.w, 32, 64);
  if (h2 == 0) {
    float4 vo;
    vo.x = ao.x + b1v.x; vo.y = ao.y + b1v.y; vo.z = ao.z + b1v.z; vo.w = ao.w + b1v.w;
    vo.x = vo.x > 0.f ? vo.x : expm1f(vo.x);
    vo.y = vo.y > 0.f ? vo.y : expm1f(vo.y);
    vo.z = vo.z > 0.f ? vo.z : expm1f(vo.z);
    vo.w = vo.w > 0.f ? vo.w : expm1f(vo.w);
    *(float4*)(hout + (size_t)d * D1 + 4 * li) = vo;
  } else {
    float4 vn;
    vn.x = an.x + b1v.x; vn.y = an.y + b1v.y; vn.z = an.z + b1v.z; vn.w = an.w + b1v.w;
    *(float4*)(nout + (size_t)d * D1 + 4 * li) = vn;
  }
}

// ---------------- layer-2 fused (ROW=16, H=1) + log_softmax epilogue ----------------
__global__ __launch_bounds__(256) void k_fused2(
    const float* __restrict__ xl, const float* __restrict__ xr,
    const float* __restrict__ att, const int* __restrict__ sperm,
    const int* __restrict__ eperm, const int* __restrict__ starts,
    const int* __restrict__ counts, const int* __restrict__ kptr,
    const float* __restrict__ bias, float* __restrict__ out0,
    float* __restrict__ out1) {
  __shared__ float sc[4][CAP];
  int w = threadIdx.x >> 6;
  int l = threadIdx.x & 63;
  int d = blockIdx.x * 4 + w;
  if (d >= NN) return;
  int st = starts[d];
  int deg = counts[d];
  if (deg > CAP) deg = CAP;
  int k = kptr[0];

  int srcreg = 0, idreg = 0x7fffffff;
  if (l < deg) { srcreg = sperm[st + l]; idreg = eperm[st + l]; }

  int g = l >> 4, li = l & 15;  // 4 row-groups of 16 lanes; lane = channel
  float xrv = xr[(size_t)d * NCLS + li];
  float attv = att[li];
  float bv2 = bias[li];

  // ---- scoring: 8 rows in flight ----
  for (int q = 0; q < deg; q += 8) {
    int r0 = q + g, r1 = q + 4 + g;
    int s0 = __shfl(srcreg, r0), s1 = __shfl(srcreg, r1);
    float x0 = (r0 < deg) ? xl[(size_t)s0 * NCLS + li] : 0.f;
    float x1 = (r1 < deg) ? xl[(size_t)s1 * NCLS + li] : 0.f;
    float a0 = x0 + xrv, a1 = x1 + xrv;
    float p0 = (a0 > 0.f ? a0 : NEG * a0) * attv;
    float p1 = (a1 > 0.f ? a1 : NEG * a1) * attv;
#pragma unroll
    for (int o = 1; o <= 8; o <<= 1) {
      p0 += __shfl_xor(p0, o, 64);
      p1 += __shfl_xor(p1, o, 64);
    }
    if (li == 0) {
      if (r0 < deg) sc[w][r0] = p0;
      if (r1 < deg) sc[w][r1] = p1;
    }
  }

  // ---- top-k + dual softmax: lane = edge ----
  float sv = (l < deg) ? sc[w][l] : NINF;
  int si = idreg;
  int rank = 0;
  for (int p = 0; p < deg; p++) {
    float bv = __shfl(sv, p);
    int bi = __shfl(si, p);
    rank += lex_gt(bv, bi, sv, si);
  }
  bool kept = (l < deg) && (rank < k);
  float mk = sv, mn = kept ? NINF : sv;
#pragma unroll
  for (int o = 1; o <= 32; o <<= 1) {
    mk = fmaxf(mk, __shfl_xor(mk, o, 64));
    mn = fmaxf(mn, __shfl_xor(mn, o, 64));
  }
  float ek = kept ? __expf(sv - mk) : 0.f;
  float en = ((l < deg) && !kept) ? __expf(sv - mn) : 0.f;
  float sk = ek, sn = en;
#pragma unroll
  for (int o = 1; o <= 32; o <<= 1) {
    sk += __shfl_xor(sk, o, 64);
    sn += __shfl_xor(sn, o, 64);
  }
  if (l < deg) sc[w][l] = kept ? ek / (sk + 1e-16f) : -(en / (sn + 1e-16f));

  // ---- aggregation ----
  float ao = 0.f, an = 0.f;
  for (int q = 0; q < deg; q += 4) {
    int r = q + g;
    int s = __shfl(srcreg, r);
    if (r < deg) {
      float wv = sc[w][r];
      float xv = xl[(size_t)s * NCLS + li];
      if (wv > 0.f) ao += wv * xv; else an -= wv * xv;
    }
  }
  ao += __shfl_xor(ao, 16, 64); ao += __shfl_xor(ao, 32, 64);
  an += __shfl_xor(an, 16, 64); an += __shfl_xor(an, 32, 64);
  float vo = ao + bv2, vn = an + bv2;
  // log_softmax over the 16-lane group
  float mo = vo, mv = vn;
#pragma unroll
  for (int o = 1; o <= 8; o <<= 1) {
    mo = fmaxf(mo, __shfl_xor(mo, o, 64));
    mv = fmaxf(mv, __shfl_xor(mv, o, 64));
  }
  float eo = __expf(vo - mo), ev = __expf(vn - mv);
#pragma unroll
  for (int o = 1; o <= 8; o <<= 1) {
    eo += __shfl_xor(eo, o, 64);
    ev += __shfl_xor(ev, o, 64);
  }
  if (g == 0) out0[(size_t)d * NCLS + li] = vo - (mo + logf(eo));
  if (g == 1) out1[(size_t)d * NCLS + li] = vn - (mv + logf(ev));
}

// ---------------- row log_softmax over 16 (n1 only) ----------------
__global__ void k_lsm(const float* __restrict__ in, float* __restrict__ out) {
  int r = blockIdx.x * 256 + threadIdx.x;
  if (r >= NN) return;
  const float4* p = (const float4*)(in + (size_t)r * NCLS);
  float4 a = p[0], b = p[1], c = p[2], d4 = p[3];
  float vals[16] = {a.x, a.y, a.z, a.w, b.x, b.y, b.z, b.w,
                    c.x, c.y, c.z, c.w, d4.x, d4.y, d4.z, d4.w};
  float m = vals[0];
#pragma unroll
  for (int i = 1; i < 16; i++) m = fmaxf(m, vals[i]);
  float s = 0.f;
#pragma unroll
  for (int i = 0; i < 16; i++) s += expf(vals[i] - m);
  float l = m + logf(s);
  float* op = out + (size_t)r * NCLS;
#pragma unroll
  for (int i = 0; i < 16; i++) op[i] = vals[i] - l;
}

extern "C" void kernel_launch(void* const* d_in, const int* in_sizes, int n_in,
                              void* d_out, int out_size, void* d_ws, size_t ws_size,
                              hipStream_t stream) {
  (void)in_sizes; (void)n_in; (void)out_size; (void)ws_size;
  const float* x    = (const float*)d_in[0];
  const int*   ei   = (const int*)d_in[1];
  const int*   kptr = (const int*)d_in[2];
  const float* Wl1  = (const float*)d_in[3];
  const float* Wr1  = (const float*)d_in[4];
  const float* att1 = (const float*)d_in[5];
  const float* b1   = (const float*)d_in[6];
  const float* Wl2  = (const float*)d_in[7];
  const float* Wr2  = (const float*)d_in[8];
  const float* att2 = (const float*)d_in[9];
  const float* b2   = (const float*)d_in[10];
  const float* l1w  = (const float*)d_in[11];
  const float* l1b  = (const float*)d_in[12];
  const float* l2w  = (const float*)d_in[13];
  const float* l2b  = (const float*)d_in[14];
  const int* srcv = ei;
  const int* dstv = ei + NE;

  char* wp = (char*)d_ws;
  auto alloc = [&](size_t n) { char* p = wp; wp += (n + 255) & ~(size_t)255; return p; };
  float* xl1    = (float*)alloc((size_t)NN * D1 * 4);
  float* bufB   = (float*)alloc((size_t)NN * D1 * 4);  // xr1 -> h (same-row in-wave)
  float* noise1 = (float*)alloc((size_t)NN * D1 * 4);
  float* t1     = (float*)alloc((size_t)NN * D1 * 4);  // mlp hidden -> xl2/xr2
  int* counts = (int*)alloc((size_t)NN * 4);
  int* starts = (int*)alloc((size_t)NN * 4);
  int* cursor = (int*)alloc((size_t)NN * 4);
  int* eperm  = (int*)alloc((size_t)NE * 4);
  int* sperm  = (int*)alloc((size_t)NE * 4);

  // CSR build (by dst)
  hipMemsetAsync(counts, 0, (size_t)NN * 4, stream);
  k_count<<<(NE + 255) / 256, 256, 0, stream>>>(dstv, counts);
  k_scan<<<1, 1024, 0, stream>>>(counts, starts, cursor);
  k_scatter<<<(NE + 255) / 256, 256, 0, stream>>>(srcv, dstv, cursor, eperm, sperm);

  // Layer 1 node transforms
  dim3 gbig(D1 / 64, (NN + 63) / 64);
  k_gemm<64, 64, 32, 4, 4, 0><<<gbig, 256, 0, stream>>>(x, Wl1, nullptr, xl1, NN, D1, FIN);
  k_gemm<64, 64, 32, 4, 4, 0><<<gbig, 256, 0, stream>>>(x, Wr1, nullptr, bufB, NN, D1, FIN);

  // Layer 1 fused edge pipeline
  k_fused1<<<(NN + 3) / 4, 256, 0, stream>>>(xl1, bufB, att1, sperm, eperm,
                                             starts, counts, kptr, b1, bufB, noise1);

  // MLP on noise1
  k_gemm<64, 64, 32, 4, 4, 1><<<gbig, 256, 0, stream>>>(noise1, l1w, l1b, t1, NN, 128, 128);
  float* n1v = noise1;
  dim3 gsm(1, (NN + 127) / 128);
  k_gemm<128, 16, 32, 4, 2, 0><<<gsm, 256, 0, stream>>>(t1, l2w, l2b, n1v, NN, NCLS, 128);

  // Layer 2 node transforms (t1 free after lin2)
  float* xl2 = t1;
  float* xr2 = t1 + (size_t)NN * NCLS;
  k_gemm<128, 16, 32, 4, 2, 0><<<gsm, 256, 0, stream>>>(bufB, Wl2, nullptr, xl2, NN, NCLS, D1);
  k_gemm<128, 16, 32, 4, 2, 0><<<gsm, 256, 0, stream>>>(bufB, Wr2, nullptr, xr2, NN, NCLS, D1);

  // Layer 2 fused edge pipeline (+log_softmax epilogue) -> final outputs
  float* o = (float*)d_out;
  k_fused2<<<(NN + 3) / 4, 256, 0, stream>>>(xl2, xr2, att2, sperm, eperm, starts,
                                             counts, kptr, b2, o,
                                             o + (size_t)2 * NN * NCLS);

  // n1 log_softmax
  k_lsm<<<(NN + 255) / 256, 256, 0, stream>>>(n1v, o + (size_t)NN * NCLS);
}

// Round 4
// 508.184 us; speedup vs baseline: 2.4073x; 1.2446x over previous
//
#include <hip/hip_runtime.h>
#include <math.h>

#define NN 50000
#define NE 800000
#define FIN 128
#define HEADS 4
#define HID 32
#define D1 128
#define NCLS 16
#define NEG 0.2f
#define NINF (-3.402823466e38f)
#define CAP 64
#define SB 256
#define NSB ((NN + SB - 1) / SB)  // 196

// ---------------- CSR build ----------------
__global__ void k_count(const int* __restrict__ dst, int* __restrict__ counts) {
  int j = blockIdx.x * 256 + threadIdx.x;
  if (j < NE) atomicAdd(&counts[dst[j]], 1);
}

// 3-phase parallel exclusive scan over counts[NN]
__global__ void k_scanA(const int* __restrict__ counts, int* __restrict__ bsum) {
  int b = blockIdx.x, t = threadIdx.x;
  int idx = b * SB + t;
  int v = idx < NN ? counts[idx] : 0;
  __shared__ int ws[4];
#pragma unroll
  for (int o = 1; o <= 32; o <<= 1) v += __shfl_xor(v, o, 64);
  if ((t & 63) == 0) ws[t >> 6] = v;
  __syncthreads();
  if (t == 0) bsum[b] = ws[0] + ws[1] + ws[2] + ws[3];
}

__global__ void k_scanB(const int* __restrict__ bsum, int* __restrict__ boff) {
  int t = threadIdx.x;
  int v = t < NSB ? bsum[t] : 0;
  __shared__ int tmp[256];
  tmp[t] = v;
  __syncthreads();
  for (int o = 1; o < 256; o <<= 1) {
    int u = t >= o ? tmp[t - o] : 0;
    __syncthreads();
    tmp[t] += u;
    __syncthreads();
  }
  if (t < NSB) boff[t] = tmp[t] - v;  // exclusive
}

__global__ void k_scanC(const int* __restrict__ counts, const int* __restrict__ boff,
                        int* __restrict__ starts, int* __restrict__ cursor) {
  int b = blockIdx.x, t = threadIdx.x;
  int idx = b * SB + t;
  int v = idx < NN ? counts[idx] : 0;
  __shared__ int tmp[256];
  tmp[t] = v;
  __syncthreads();
  for (int o = 1; o < 256; o <<= 1) {
    int u = t >= o ? tmp[t - o] : 0;
    __syncthreads();
    tmp[t] += u;
    __syncthreads();
  }
  int ex = tmp[t] - v + boff[b];
  if (idx < NN) { starts[idx] = ex; cursor[idx] = ex; }
}

__global__ void k_scatter(const int* __restrict__ src, const int* __restrict__ dst,
                          int* __restrict__ cursor, int* __restrict__ eperm,
                          int* __restrict__ sperm) {
  int j = blockIdx.x * 256 + threadIdx.x;
  if (j < NE) {
    int p = atomicAdd(&cursor[dst[j]], 1);
    eperm[p] = j;
    sperm[p] = src[j];
  }
}

// ---------------- fp32 tiled GEMM ----------------
template <int BM, int BN, int BK, int TM, int TN, int ACT>
__global__ __launch_bounds__(256) void k_gemm(const float* __restrict__ A,
                                              const float* __restrict__ B,
                                              const float* __restrict__ bias,
                                              float* __restrict__ C, int M, int N, int K) {
  constexpr int NT = (BM / TM) * (BN / TN);
  static_assert(NT == 256, "block must be 256 threads");
  __shared__ float As[BK][BM + 4];
  __shared__ float Bs[BK][BN];
  int tid = threadIdx.x;
  int bm = blockIdx.y * BM, bn = blockIdx.x * BN;
  constexpr int TX = BN / TN;
  int tn = (tid % TX) * TN;
  int tm = (tid / TX) * TM;
  float acc[TM][TN];
#pragma unroll
  for (int i = 0; i < TM; i++)
#pragma unroll
    for (int j = 0; j < TN; j++) acc[i][j] = 0.f;

  for (int k0 = 0; k0 < K; k0 += BK) {
    constexpr int AV = BM * BK / 4;
    for (int i = tid; i < AV; i += NT) {
      int r = i / (BK / 4);
      int c4 = (i % (BK / 4)) * 4;
      float4 v = make_float4(0.f, 0.f, 0.f, 0.f);
      int gr = bm + r;
      if (gr < M) v = *(const float4*)(A + (size_t)gr * K + k0 + c4);
      As[c4 + 0][r] = v.x; As[c4 + 1][r] = v.y; As[c4 + 2][r] = v.z; As[c4 + 3][r] = v.w;
    }
    constexpr int BV = BK * BN / 4;
    for (int i = tid; i < BV; i += NT) {
      int r = i / (BN / 4), c4 = (i % (BN / 4)) * 4;
      float4 v = *(const float4*)(B + (size_t)(k0 + r) * N + bn + c4);
      Bs[r][c4 + 0] = v.x; Bs[r][c4 + 1] = v.y; Bs[r][c4 + 2] = v.z; Bs[r][c4 + 3] = v.w;
    }
    __syncthreads();
#pragma unroll
    for (int kk = 0; kk < BK; kk++) {
      float ra[TM], rb[TN];
#pragma unroll
      for (int i = 0; i < TM; i++) ra[i] = As[kk][tm + i];
#pragma unroll
      for (int j = 0; j < TN; j++) rb[j] = Bs[kk][tn + j];
#pragma unroll
      for (int i = 0; i < TM; i++)
#pragma unroll
        for (int j = 0; j < TN; j++) acc[i][j] += ra[i] * rb[j];
    }
    __syncthreads();
  }
#pragma unroll
  for (int i = 0; i < TM; i++) {
    int gr = bm + tm + i;
    if (gr >= M) continue;
#pragma unroll
    for (int j = 0; j < TN; j++) {
      float v = acc[i][j];
      if (bias) v += bias[bn + tn + j];
      if (ACT == 1) v = v > 0.f ? v : expm1f(v);
      C[(size_t)gr * N + bn + tn + j] = v;
    }
  }
}

__device__ __forceinline__ bool lex_gt(float av, int ai, float bv, int bi) {
  return (av > bv) || (av == bv && ai < bi);
}

// ---------------- layer-1 fused: wave per dst, 4 dst per block ----------------
__global__ __launch_bounds__(256) void k_fused1(
    const float* __restrict__ xl, const float* __restrict__ xr,
    const float* __restrict__ att, const int* __restrict__ sperm,
    const int* __restrict__ eperm, const int* __restrict__ starts,
    const int* __restrict__ counts, const int* __restrict__ kptr,
    const float* __restrict__ bias, float* __restrict__ hout,
    float* __restrict__ nout) {
  __shared__ float sc[4][CAP][4];  // [wave][edge][head], wave-private
  int w = threadIdx.x >> 6;
  int l = threadIdx.x & 63;
  int d = blockIdx.x * 4 + w;
  if (d >= NN) return;  // wave-uniform
  int st = starts[d];
  int deg = counts[d];
  if (deg > CAP) deg = CAP;
  int k = kptr[0];

  int srcreg = 0, idreg = 0x7fffffff;
  if (l < deg) { srcreg = sperm[st + l]; idreg = eperm[st + l]; }

  int h2 = l >> 5, li = l & 31;
  int headq = li >> 3;
  float4 xrv = *(const float4*)(xr + (size_t)d * D1 + 4 * li);
  float4 attv = *(const float4*)(att + 4 * li);
  float4 b1v = *(const float4*)(bias + 4 * li);

  // ---- scoring: 4 rows in flight per wave ----
  for (int q = 0; q < deg; q += 4) {
    int r0 = q + h2, r1 = q + 2 + h2;
    int s0 = __shfl(srcreg, r0), s1 = __shfl(srcreg, r1);
    bool v0 = r0 < deg, v1 = r1 < deg;
    float4 x0 = make_float4(0.f, 0.f, 0.f, 0.f), x1 = x0;
    if (v0) x0 = *(const float4*)(xl + (size_t)s0 * D1 + 4 * li);
    if (v1) x1 = *(const float4*)(xl + (size_t)s1 * D1 + 4 * li);
    float a0, a1, p0 = 0.f, p1 = 0.f;
    a0 = x0.x + xrv.x; p0 += (a0 > 0.f ? a0 : NEG * a0) * attv.x;
    a0 = x0.y + xrv.y; p0 += (a0 > 0.f ? a0 : NEG * a0) * attv.y;
    a0 = x0.z + xrv.z; p0 += (a0 > 0.f ? a0 : NEG * a0) * attv.z;
    a0 = x0.w + xrv.w; p0 += (a0 > 0.f ? a0 : NEG * a0) * attv.w;
    a1 = x1.x + xrv.x; p1 += (a1 > 0.f ? a1 : NEG * a1) * attv.x;
    a1 = x1.y + xrv.y; p1 += (a1 > 0.f ? a1 : NEG * a1) * attv.y;
    a1 = x1.z + xrv.z; p1 += (a1 > 0.f ? a1 : NEG * a1) * attv.z;
    a1 = x1.w + xrv.w; p1 += (a1 > 0.f ? a1 : NEG * a1) * attv.w;
#pragma unroll
    for (int o = 1; o <= 4; o <<= 1) {
      p0 += __shfl_xor(p0, o, 64);
      p1 += __shfl_xor(p1, o, 64);
    }
    if ((li & 7) == 0) {
      if (v0) sc[w][r0][headq] = p0;
      if (v1) sc[w][r1][headq] = p1;
    }
  }

  // ---- top-k + dual softmax: lane = head*16 + i, 4 slots each ----
  int hh = l >> 4, ii = l & 15;
  float sv[4]; int si[4]; int rank[4]; bool val[4];
#pragma unroll
  for (int j = 0; j < 4; j++) {
    int q = j * 16 + ii;
    val[j] = q < deg;
    sv[j] = val[j] ? sc[w][q][hh] : NINF;
    int bid = __shfl(idreg, q);
    si[j] = val[j] ? bid : 0x7fffffff;
    rank[j] = 0;
  }
#pragma unroll
  for (int ch = 0; ch < 4; ch++) {
    if (ch * 16 >= deg) break;
#pragma unroll
    for (int pp = 0; pp < 16; pp++) {
      int p = ch * 16 + pp;
      float bv = __shfl(sv[ch], hh * 16 + pp);
      int bi = __shfl(si[ch], hh * 16 + pp);
      if (p < deg) {
#pragma unroll
        for (int j = 0; j < 4; j++) rank[j] += lex_gt(bv, bi, sv[j], si[j]);
      }
    }
  }
  bool kept[4];
#pragma unroll
  for (int j = 0; j < 4; j++) kept[j] = val[j] && (rank[j] < k);
  float mk = fmaxf(fmaxf(sv[0], sv[1]), fmaxf(sv[2], sv[3]));
  float mn = NINF;
#pragma unroll
  for (int j = 0; j < 4; j++) mn = fmaxf(mn, kept[j] ? NINF : sv[j]);
#pragma unroll
  for (int o = 1; o <= 8; o <<= 1) {
    mk = fmaxf(mk, __shfl_xor(mk, o, 64));
    mn = fmaxf(mn, __shfl_xor(mn, o, 64));
  }
  float ek[4], en[4], sk = 0.f, sn = 0.f;
#pragma unroll
  for (int j = 0; j < 4; j++) {
    ek[j] = kept[j] ? __expf(sv[j] - mk) : 0.f;
    en[j] = (val[j] && !kept[j]) ? __expf(sv[j] - mn) : 0.f;
    sk += ek[j]; sn += en[j];
  }
#pragma unroll
  for (int o = 1; o <= 8; o <<= 1) {
    sk += __shfl_xor(sk, o, 64);
    sn += __shfl_xor(sn, o, 64);
  }
  float ik = 1.f / (sk + 1e-16f), inn = 1.f / (sn + 1e-16f);
#pragma unroll
  for (int j = 0; j < 4; j++) {
    if (val[j]) sc[w][j * 16 + ii][hh] = kept[j] ? ek[j] * ik : -(en[j] * inn);
  }

  // ---- aggregation (reload xl rows: L1/L2-hot from scoring) ----
  float4 ao = make_float4(0.f, 0.f, 0.f, 0.f), an = ao;
  for (int q = 0; q < deg; q += 4) {
    int r0 = q + h2, r1 = q + 2 + h2;
    int s0 = __shfl(srcreg, r0), s1 = __shfl(srcreg, r1);
    if (r0 < deg) {
      float wv = sc[w][r0][headq];
      float4 xv = *(const float4*)(xl + (size_t)s0 * D1 + 4 * li);
      float s = wv > 0.f ? wv : -wv;
      if (wv > 0.f) { ao.x += s * xv.x; ao.y += s * xv.y; ao.z += s * xv.z; ao.w += s * xv.w; }
      else          { an.x += s * xv.x; an.y += s * xv.y; an.z += s * xv.z; an.w += s * xv.w; }
    }
    if (r1 < deg) {
      float wv = sc[w][r1][headq];
      float4 xv = *(const float4*)(xl + (size_t)s1 * D1 + 4 * li);
      float s = wv > 0.f ? wv : -wv;
      if (wv > 0.f) { ao.x += s * xv.x; ao.y += s * xv.y; ao.z += s * xv.z; ao.w += s * xv.w; }
      else          { an.x += s * xv.x; an.y += s * xv.y; an.z += s * xv.z; an.w += s * xv.w; }
    }
  }
  ao.x += __shfl_xor(ao.x, 32, 64); ao.y += __shfl_xor(ao.y, 32, 64);
  ao.z += __shfl_xor(ao.z, 32, 64); ao.w += __shfl_xor(ao.w, 32, 64);
  an.x += __shfl_xor(an.x, 32, 64); an.y += __shfl_xor(an.y, 32, 64);
  an.z += __shfl_xor(an.z, 32, 64); an.w += __shfl_xor(an.w, 32, 64);
  if (h2 == 0) {
    float4 vo;
    vo.x = ao.x + b1v.x; vo.y = ao.y + b1v.y; vo.z = ao.z + b1v.z; vo.w = ao.w + b1v.w;
    vo.x = vo.x > 0.f ? vo.x : expm1f(vo.x);
    vo.y = vo.y > 0.f ? vo.y : expm1f(vo.y);
    vo.z = vo.z > 0.f ? vo.z : expm1f(vo.z);
    vo.w = vo.w > 0.f ? vo.w : expm1f(vo.w);
    *(float4*)(hout + (size_t)d * D1 + 4 * li) = vo;
  } else {
    float4 vn;
    vn.x = an.x + b1v.x; vn.y = an.y + b1v.y; vn.z = an.z + b1v.z; vn.w = an.w + b1v.w;
    *(float4*)(nout + (size_t)d * D1 + 4 * li) = vn;
  }
}

// ---------------- layer-2 fused (ROW=16, H=1) + log_softmax epilogue ----------------
__global__ __launch_bounds__(256) void k_fused2(
    const float* __restrict__ xl, const float* __restrict__ xr,
    const float* __restrict__ att, const int* __restrict__ sperm,
    const int* __restrict__ eperm, const int* __restrict__ starts,
    const int* __restrict__ counts, const int* __restrict__ kptr,
    const float* __restrict__ bias, float* __restrict__ out0,
    float* __restrict__ out1) {
  __shared__ float sc[4][CAP];
  int w = threadIdx.x >> 6;
  int l = threadIdx.x & 63;
  int d = blockIdx.x * 4 + w;
  if (d >= NN) return;
  int st = starts[d];
  int deg = counts[d];
  if (deg > CAP) deg = CAP;
  int k = kptr[0];

  int srcreg = 0, idreg = 0x7fffffff;
  if (l < deg) { srcreg = sperm[st + l]; idreg = eperm[st + l]; }

  int g = l >> 4, li = l & 15;
  float xrv = xr[(size_t)d * NCLS + li];
  float attv = att[li];
  float bv2 = bias[li];

  // ---- scoring: 8 rows in flight ----
  for (int q = 0; q < deg; q += 8) {
    int r0 = q + g, r1 = q + 4 + g;
    int s0 = __shfl(srcreg, r0), s1 = __shfl(srcreg, r1);
    float x0 = (r0 < deg) ? xl[(size_t)s0 * NCLS + li] : 0.f;
    float x1 = (r1 < deg) ? xl[(size_t)s1 * NCLS + li] : 0.f;
    float a0 = x0 + xrv, a1 = x1 + xrv;
    float p0 = (a0 > 0.f ? a0 : NEG * a0) * attv;
    float p1 = (a1 > 0.f ? a1 : NEG * a1) * attv;
#pragma unroll
    for (int o = 1; o <= 8; o <<= 1) {
      p0 += __shfl_xor(p0, o, 64);
      p1 += __shfl_xor(p1, o, 64);
    }
    if (li == 0) {
      if (r0 < deg) sc[w][r0] = p0;
      if (r1 < deg) sc[w][r1] = p1;
    }
  }

  // ---- top-k + dual softmax: lane = edge ----
  float sv = (l < deg) ? sc[w][l] : NINF;
  int si = idreg;
  int rank = 0;
  for (int p = 0; p < deg; p++) {
    float bv = __shfl(sv, p);
    int bi = __shfl(si, p);
    rank += lex_gt(bv, bi, sv, si);
  }
  bool kept = (l < deg) && (rank < k);
  float mk = sv, mn = kept ? NINF : sv;
#pragma unroll
  for (int o = 1; o <= 32; o <<= 1) {
    mk = fmaxf(mk, __shfl_xor(mk, o, 64));
    mn = fmaxf(mn, __shfl_xor(mn, o, 64));
  }
  float ek = kept ? __expf(sv - mk) : 0.f;
  float en = ((l < deg) && !kept) ? __expf(sv - mn) : 0.f;
  float sk = ek, sn = en;
#pragma unroll
  for (int o = 1; o <= 32; o <<= 1) {
    sk += __shfl_xor(sk, o, 64);
    sn += __shfl_xor(sn, o, 64);
  }
  if (l < deg) sc[w][l] = kept ? ek / (sk + 1e-16f) : -(en / (sn + 1e-16f));

  // ---- aggregation ----
  float ao = 0.f, an = 0.f;
  for (int q = 0; q < deg; q += 4) {
    int r = q + g;
    int s = __shfl(srcreg, r);
    if (r < deg) {
      float wv = sc[w][r];
      float xv = xl[(size_t)s * NCLS + li];
      if (wv > 0.f) ao += wv * xv; else an -= wv * xv;
    }
  }
  ao += __shfl_xor(ao, 16, 64); ao += __shfl_xor(ao, 32, 64);
  an += __shfl_xor(an, 16, 64); an += __shfl_xor(an, 32, 64);
  float vo = ao + bv2, vn = an + bv2;
  float mo = vo, mv = vn;
#pragma unroll
  for (int o = 1; o <= 8; o <<= 1) {
    mo = fmaxf(mo, __shfl_xor(mo, o, 64));
    mv = fmaxf(mv, __shfl_xor(mv, o, 64));
  }
  float eo = __expf(vo - mo), ev = __expf(vn - mv);
#pragma unroll
  for (int o = 1; o <= 8; o <<= 1) {
    eo += __shfl_xor(eo, o, 64);
    ev += __shfl_xor(ev, o, 64);
  }
  if (g == 0) out0[(size_t)d * NCLS + li] = vo - (mo + logf(eo));
  if (g == 1) out1[(size_t)d * NCLS + li] = vn - (mv + logf(ev));
}

// ---------------- row log_softmax over 16 (n1 only) ----------------
__global__ void k_lsm(const float* __restrict__ in, float* __restrict__ out) {
  int r = blockIdx.x * 256 + threadIdx.x;
  if (r >= NN) return;
  const float4* p = (const float4*)(in + (size_t)r * NCLS);
  float4 a = p[0], b = p[1], c = p[2], d4 = p[3];
  float vals[16] = {a.x, a.y, a.z, a.w, b.x, b.y, b.z, b.w,
                    c.x, c.y, c.z, c.w, d4.x, d4.y, d4.z, d4.w};
  float m = vals[0];
#pragma unroll
  for (int i = 1; i < 16; i++) m = fmaxf(m, vals[i]);
  float s = 0.f;
#pragma unroll
  for (int i = 0; i < 16; i++) s += expf(vals[i] - m);
  float l = m + logf(s);
  float* op = out + (size_t)r * NCLS;
#pragma unroll
  for (int i = 0; i < 16; i++) op[i] = vals[i] - l;
}

extern "C" void kernel_launch(void* const* d_in, const int* in_sizes, int n_in,
                              void* d_out, int out_size, void* d_ws, size_t ws_size,
                              hipStream_t stream) {
  (void)in_sizes; (void)n_in; (void)out_size; (void)ws_size;
  const float* x    = (const float*)d_in[0];
  const int*   ei   = (const int*)d_in[1];
  const int*   kptr = (const int*)d_in[2];
  const float* Wl1  = (const float*)d_in[3];
  const float* Wr1  = (const float*)d_in[4];
  const float* att1 = (const float*)d_in[5];
  const float* b1   = (const float*)d_in[6];
  const float* Wl2  = (const float*)d_in[7];
  const float* Wr2  = (const float*)d_in[8];
  const float* att2 = (const float*)d_in[9];
  const float* b2   = (const float*)d_in[10];
  const float* l1w  = (const float*)d_in[11];
  const float* l1b  = (const float*)d_in[12];
  const float* l2w  = (const float*)d_in[13];
  const float* l2b  = (const float*)d_in[14];
  const int* srcv = ei;
  const int* dstv = ei + NE;

  char* wp = (char*)d_ws;
  auto alloc = [&](size_t n) { char* p = wp; wp += (n + 255) & ~(size_t)255; return p; };
  float* xl1    = (float*)alloc((size_t)NN * D1 * 4);
  float* bufB   = (float*)alloc((size_t)NN * D1 * 4);  // xr1 -> h (same-row in-wave)
  float* noise1 = (float*)alloc((size_t)NN * D1 * 4);
  float* t1     = (float*)alloc((size_t)NN * D1 * 4);  // mlp hidden -> xl2/xr2
  int* counts = (int*)alloc((size_t)NN * 4);
  int* starts = (int*)alloc((size_t)NN * 4);
  int* cursor = (int*)alloc((size_t)NN * 4);
  int* eperm  = (int*)alloc((size_t)NE * 4);
  int* sperm  = (int*)alloc((size_t)NE * 4);
  int* bsum   = (int*)alloc((size_t)NSB * 4);
  int* boff   = (int*)alloc((size_t)NSB * 4);

  // CSR build (by dst) — parallel 3-phase scan
  hipMemsetAsync(counts, 0, (size_t)NN * 4, stream);
  k_count<<<(NE + 255) / 256, 256, 0, stream>>>(dstv, counts);
  k_scanA<<<NSB, 256, 0, stream>>>(counts, bsum);
  k_scanB<<<1, 256, 0, stream>>>(bsum, boff);
  k_scanC<<<NSB, 256, 0, stream>>>(counts, boff, starts, cursor);
  k_scatter<<<(NE + 255) / 256, 256, 0, stream>>>(srcv, dstv, cursor, eperm, sperm);

  // Layer 1 node transforms
  dim3 gbig(D1 / 64, (NN + 63) / 64);
  k_gemm<64, 64, 32, 4, 4, 0><<<gbig, 256, 0, stream>>>(x, Wl1, nullptr, xl1, NN, D1, FIN);
  k_gemm<64, 64, 32, 4, 4, 0><<<gbig, 256, 0, stream>>>(x, Wr1, nullptr, bufB, NN, D1, FIN);

  // Layer 1 fused edge pipeline
  k_fused1<<<(NN + 3) / 4, 256, 0, stream>>>(xl1, bufB, att1, sperm, eperm,
                                             starts, counts, kptr, b1, bufB, noise1);

  // MLP on noise1
  k_gemm<64, 64, 32, 4, 4, 1><<<gbig, 256, 0, stream>>>(noise1, l1w, l1b, t1, NN, 128, 128);
  float* n1v = noise1;
  dim3 gsm(1, (NN + 127) / 128);
  k_gemm<128, 16, 32, 4, 2, 0><<<gsm, 256, 0, stream>>>(t1, l2w, l2b, n1v, NN, NCLS, 128);

  // Layer 2 node transforms (t1 free after lin2)
  float* xl2 = t1;
  float* xr2 = t1 + (size_t)NN * NCLS;
  k_gemm<128, 16, 32, 4, 2, 0><<<gsm, 256, 0, stream>>>(bufB, Wl2, nullptr, xl2, NN, NCLS, D1);
  k_gemm<128, 16, 32, 4, 2, 0><<<gsm, 256, 0, stream>>>(bufB, Wr2, nullptr, xr2, NN, NCLS, D1);

  // Layer 2 fused edge pipeline (+log_softmax epilogue) -> final outputs
  float* o = (float*)d_out;
  k_fused2<<<(NN + 3) / 4, 256, 0, stream>>>(xl2, xr2, att2, sperm, eperm, starts,
                                             counts, kptr, b2, o,
                                             o + (size_t)2 * NN * NCLS);

  // n1 log_softmax
  k_lsm<<<(NN + 255) / 256, 256, 0, stream>>>(n1v, o + (size_t)NN * NCLS);
}

// Round 5
// 488.571 us; speedup vs baseline: 2.5039x; 1.0401x over previous
//
#include <hip/hip_runtime.h>
#include <math.h>

#define NN 50000
#define NE 800000
#define FIN 128
#define HEADS 4
#define HID 32
#define D1 128
#define NCLS 16
#define NEG 0.2f
#define NINF (-3.402823466e38f)
#define CAP 64
#define SB 256
#define NSB ((NN + SB - 1) / SB)  // 196

// ---------------- CSR build ----------------
__global__ void k_count(const int* __restrict__ dst, int* __restrict__ counts) {
  int j = blockIdx.x * 256 + threadIdx.x;
  if (j < NE) atomicAdd(&counts[dst[j]], 1);
}

__global__ void k_scanA(const int* __restrict__ counts, int* __restrict__ bsum) {
  int b = blockIdx.x, t = threadIdx.x;
  int idx = b * SB + t;
  int v = idx < NN ? counts[idx] : 0;
  __shared__ int ws[4];
#pragma unroll
  for (int o = 1; o <= 32; o <<= 1) v += __shfl_xor(v, o, 64);
  if ((t & 63) == 0) ws[t >> 6] = v;
  __syncthreads();
  if (t == 0) bsum[b] = ws[0] + ws[1] + ws[2] + ws[3];
}

__global__ void k_scanB(const int* __restrict__ bsum, int* __restrict__ boff) {
  int t = threadIdx.x;
  int v = t < NSB ? bsum[t] : 0;
  __shared__ int tmp[256];
  tmp[t] = v;
  __syncthreads();
  for (int o = 1; o < 256; o <<= 1) {
    int u = t >= o ? tmp[t - o] : 0;
    __syncthreads();
    tmp[t] += u;
    __syncthreads();
  }
  if (t < NSB) boff[t] = tmp[t] - v;  // exclusive
}

__global__ void k_scanC(const int* __restrict__ counts, const int* __restrict__ boff,
                        int* __restrict__ starts, int* __restrict__ cursor) {
  int b = blockIdx.x, t = threadIdx.x;
  int idx = b * SB + t;
  int v = idx < NN ? counts[idx] : 0;
  __shared__ int tmp[256];
  tmp[t] = v;
  __syncthreads();
  for (int o = 1; o < 256; o <<= 1) {
    int u = t >= o ? tmp[t - o] : 0;
    __syncthreads();
    tmp[t] += u;
    __syncthreads();
  }
  int ex = tmp[t] - v + boff[b];
  if (idx < NN) { starts[idx] = ex; cursor[idx] = ex; }
}

__global__ void k_scatter(const int* __restrict__ src, const int* __restrict__ dst,
                          int* __restrict__ cursor, int* __restrict__ eperm,
                          int* __restrict__ sperm) {
  int j = blockIdx.x * 256 + threadIdx.x;
  if (j < NE) {
    int p = atomicAdd(&cursor[dst[j]], 1);
    eperm[p] = j;
    sperm[p] = src[j];
  }
}

// ---------------- fp32 tiled GEMM, dual-B (cols < N1 from B1, else B2) ----------------
// float4 LDS fragment reads: As row stride (BM+4)*4B and Bs row stride BN*4B are
// 16B-multiples; tm,tn multiples of 4 -> ds_read_b128.
template <int BM, int BN, int BK, int TM, int TN, int ACT>
__global__ __launch_bounds__(256) void k_gemm2(
    const float* __restrict__ A, const float* __restrict__ B1,
    const float* __restrict__ B2, int N1, int s1, int s2,
    const float* __restrict__ bias, float* __restrict__ C, int M, int N, int K) {
  constexpr int NT = (BM / TM) * (BN / TN);
  static_assert(NT == 256, "block must be 256 threads");
  static_assert(TM % 4 == 0 && TN % 4 == 0, "float4 fragments");
  __shared__ float As[BK][BM + 4];
  __shared__ float Bs[BK][BN];
  int tid = threadIdx.x;
  int bm = blockIdx.y * BM, bn = blockIdx.x * BN;
  constexpr int TX = BN / TN;
  int tn = (tid % TX) * TN;
  int tm = (tid / TX) * TM;
  float acc[TM][TN];
#pragma unroll
  for (int i = 0; i < TM; i++)
#pragma unroll
    for (int j = 0; j < TN; j++) acc[i][j] = 0.f;

  for (int k0 = 0; k0 < K; k0 += BK) {
    constexpr int AV = BM * BK / 4;
    for (int i = tid; i < AV; i += NT) {
      int r = i / (BK / 4);
      int c4 = (i % (BK / 4)) * 4;
      float4 v = make_float4(0.f, 0.f, 0.f, 0.f);
      int gr = bm + r;
      if (gr < M) v = *(const float4*)(A + (size_t)gr * K + k0 + c4);
      As[c4 + 0][r] = v.x; As[c4 + 1][r] = v.y; As[c4 + 2][r] = v.z; As[c4 + 3][r] = v.w;
    }
    constexpr int BV = BK * BN / 4;
    for (int i = tid; i < BV; i += NT) {
      int r = i / (BN / 4), c4 = (i % (BN / 4)) * 4;
      int gc = bn + c4, gk = k0 + r;
      float4 v = (gc < N1) ? *(const float4*)(B1 + (size_t)gk * s1 + gc)
                           : *(const float4*)(B2 + (size_t)gk * s2 + (gc - N1));
      Bs[r][c4 + 0] = v.x; Bs[r][c4 + 1] = v.y; Bs[r][c4 + 2] = v.z; Bs[r][c4 + 3] = v.w;
    }
    __syncthreads();
#pragma unroll
    for (int kk = 0; kk < BK; kk++) {
      float ra[TM], rb[TN];
#pragma unroll
      for (int i = 0; i < TM; i += 4)
        *(float4*)&ra[i] = *(const float4*)&As[kk][tm + i];
#pragma unroll
      for (int j = 0; j < TN; j += 4)
        *(float4*)&rb[j] = *(const float4*)&Bs[kk][tn + j];
#pragma unroll
      for (int i = 0; i < TM; i++)
#pragma unroll
        for (int j = 0; j < TN; j++) acc[i][j] += ra[i] * rb[j];
    }
    __syncthreads();
  }
#pragma unroll
  for (int i = 0; i < TM; i++) {
    int gr = bm + tm + i;
    if (gr >= M) continue;
#pragma unroll
    for (int j = 0; j < TN; j += 4) {
      float4 v;
      v.x = acc[i][j + 0]; v.y = acc[i][j + 1]; v.z = acc[i][j + 2]; v.w = acc[i][j + 3];
      if (bias) {
        v.x += bias[bn + tn + j + 0]; v.y += bias[bn + tn + j + 1];
        v.z += bias[bn + tn + j + 2]; v.w += bias[bn + tn + j + 3];
      }
      if (ACT == 1) {
        v.x = v.x > 0.f ? v.x : expm1f(v.x);
        v.y = v.y > 0.f ? v.y : expm1f(v.y);
        v.z = v.z > 0.f ? v.z : expm1f(v.z);
        v.w = v.w > 0.f ? v.w : expm1f(v.w);
      }
      *(float4*)(C + (size_t)gr * N + bn + tn + j) = v;
    }
  }
}

__device__ __forceinline__ bool lex_gt(float av, int ai, float bv, int bi) {
  return (av > bv) || (av == bv && ai < bi);
}

// ---------------- layer-1 fused: wave per dst, 4 dst per block ----------------
// xlr: [NN][256], cols 0-127 = xl, 128-255 = xr.
__global__ __launch_bounds__(256) void k_fused1(
    const float* __restrict__ xlr, const float* __restrict__ att,
    const int* __restrict__ sperm, const int* __restrict__ eperm,
    const int* __restrict__ starts, const int* __restrict__ counts,
    const int* __restrict__ kptr, const float* __restrict__ bias,
    float* __restrict__ hout, float* __restrict__ nout) {
  __shared__ float sc[4][CAP][4];  // [wave][edge][head], wave-private
  int w = threadIdx.x >> 6;
  int l = threadIdx.x & 63;
  int d = blockIdx.x * 4 + w;
  if (d >= NN) return;  // wave-uniform
  int st = starts[d];
  int deg = counts[d];
  if (deg > CAP) deg = CAP;
  int k = kptr[0];

  int srcreg = 0, idreg = 0x7fffffff;
  if (l < deg) { srcreg = sperm[st + l]; idreg = eperm[st + l]; }

  int h2 = l >> 5, li = l & 31;
  int headq = li >> 3;
  float4 xrv = *(const float4*)(xlr + (size_t)d * 256 + 128 + 4 * li);
  float4 attv = *(const float4*)(att + 4 * li);
  float4 b1v = *(const float4*)(bias + 4 * li);

  // ---- scoring: 8 rows in flight per wave (lrelu = max(a, 0.2a)) ----
  for (int q = 0; q < deg; q += 8) {
    int rr[4]; int ssr[4]; bool vv[4]; float4 xv[4]; float pp[4];
#pragma unroll
    for (int j = 0; j < 4; j++) {
      rr[j] = q + 2 * j + h2;
      ssr[j] = __shfl(srcreg, rr[j]);
      vv[j] = rr[j] < deg;
      xv[j] = make_float4(0.f, 0.f, 0.f, 0.f);
      if (vv[j]) xv[j] = *(const float4*)(xlr + (size_t)ssr[j] * 256 + 4 * li);
    }
#pragma unroll
    for (int j = 0; j < 4; j++) {
      float a, p = 0.f;
      a = xv[j].x + xrv.x; p += fmaxf(a, NEG * a) * attv.x;
      a = xv[j].y + xrv.y; p += fmaxf(a, NEG * a) * attv.y;
      a = xv[j].z + xrv.z; p += fmaxf(a, NEG * a) * attv.z;
      a = xv[j].w + xrv.w; p += fmaxf(a, NEG * a) * attv.w;
      pp[j] = p;
    }
#pragma unroll
    for (int o = 1; o <= 4; o <<= 1) {
#pragma unroll
      for (int j = 0; j < 4; j++) pp[j] += __shfl_xor(pp[j], o, 64);
    }
    if ((li & 7) == 0) {
#pragma unroll
      for (int j = 0; j < 4; j++)
        if (vv[j]) sc[w][rr[j]][headq] = pp[j];
    }
  }

  // ---- top-k + dual softmax: lane = head*16 + i, 4 slots each ----
  int hh = l >> 4, ii = l & 15;
  float sv[4]; int si[4]; int rank[4]; bool val[4];
#pragma unroll
  for (int j = 0; j < 4; j++) {
    int q = j * 16 + ii;
    val[j] = q < deg;
    sv[j] = val[j] ? sc[w][q][hh] : NINF;
    int bid = __shfl(idreg, q);
    si[j] = val[j] ? bid : 0x7fffffff;
    rank[j] = 0;
  }
#pragma unroll
  for (int ch = 0; ch < 4; ch++) {
    if (ch * 16 >= deg) break;
#pragma unroll
    for (int pp = 0; pp < 16; pp++) {
      int p = ch * 16 + pp;
      float bv = __shfl(sv[ch], hh * 16 + pp);
      int bi = __shfl(si[ch], hh * 16 + pp);
      if (p < deg) {
#pragma unroll
        for (int j = 0; j < 4; j++) rank[j] += lex_gt(bv, bi, sv[j], si[j]);
      }
    }
  }
  bool kept[4];
#pragma unroll
  for (int j = 0; j < 4; j++) kept[j] = val[j] && (rank[j] < k);
  float mk = fmaxf(fmaxf(sv[0], sv[1]), fmaxf(sv[2], sv[3]));
  float mn = NINF;
#pragma unroll
  for (int j = 0; j < 4; j++) mn = fmaxf(mn, kept[j] ? NINF : sv[j]);
#pragma unroll
  for (int o = 1; o <= 8; o <<= 1) {
    mk = fmaxf(mk, __shfl_xor(mk, o, 64));
    mn = fmaxf(mn, __shfl_xor(mn, o, 64));
  }
  float ek[4], en[4], sk = 0.f, sn = 0.f;
#pragma unroll
  for (int j = 0; j < 4; j++) {
    ek[j] = kept[j] ? __expf(sv[j] - mk) : 0.f;
    en[j] = (val[j] && !kept[j]) ? __expf(sv[j] - mn) : 0.f;
    sk += ek[j]; sn += en[j];
  }
#pragma unroll
  for (int o = 1; o <= 8; o <<= 1) {
    sk += __shfl_xor(sk, o, 64);
    sn += __shfl_xor(sn, o, 64);
  }
  float ik = 1.f / (sk + 1e-16f), inn = 1.f / (sn + 1e-16f);
#pragma unroll
  for (int j = 0; j < 4; j++) {
    if (val[j]) sc[w][j * 16 + ii][hh] = kept[j] ? ek[j] * ik : -(en[j] * inn);
  }

  // ---- aggregation (branchless dual accumulate) ----
  float4 ao = make_float4(0.f, 0.f, 0.f, 0.f), an = ao;
  for (int q = 0; q < deg; q += 4) {
    int r0 = q + h2, r1 = q + 2 + h2;
    int s0 = __shfl(srcreg, r0), s1 = __shfl(srcreg, r1);
    if (r0 < deg) {
      float wv = sc[w][r0][headq];
      float pw = fmaxf(wv, 0.f), nw = pw - wv;
      float4 xv = *(const float4*)(xlr + (size_t)s0 * 256 + 4 * li);
      ao.x += pw * xv.x; ao.y += pw * xv.y; ao.z += pw * xv.z; ao.w += pw * xv.w;
      an.x += nw * xv.x; an.y += nw * xv.y; an.z += nw * xv.z; an.w += nw * xv.w;
    }
    if (r1 < deg) {
      float wv = sc[w][r1][headq];
      float pw = fmaxf(wv, 0.f), nw = pw - wv;
      float4 xv = *(const float4*)(xlr + (size_t)s1 * 256 + 4 * li);
      ao.x += pw * xv.x; ao.y += pw * xv.y; ao.z += pw * xv.z; ao.w += pw * xv.w;
      an.x += nw * xv.x; an.y += nw * xv.y; an.z += nw * xv.z; an.w += nw * xv.w;
    }
  }
  ao.x += __shfl_xor(ao.x, 32, 64); ao.y += __shfl_xor(ao.y, 32, 64);
  ao.z += __shfl_xor(ao.z, 32, 64); ao.w += __shfl_xor(ao.w, 32, 64);
  an.x += __shfl_xor(an.x, 32, 64); an.y += __shfl_xor(an.y, 32, 64);
  an.z += __shfl_xor(an.z, 32, 64); an.w += __shfl_xor(an.w, 32, 64);
  if (h2 == 0) {
    float4 vo;
    vo.x = ao.x + b1v.x; vo.y = ao.y + b1v.y; vo.z = ao.z + b1v.z; vo.w = ao.w + b1v.w;
    vo.x = vo.x > 0.f ? vo.x : expm1f(vo.x);
    vo.y = vo.y > 0.f ? vo.y : expm1f(vo.y);
    vo.z = vo.z > 0.f ? vo.z : expm1f(vo.z);
    vo.w = vo.w > 0.f ? vo.w : expm1f(vo.w);
    *(float4*)(hout + (size_t)d * D1 + 4 * li) = vo;
  } else {
    float4 vn;
    vn.x = an.x + b1v.x; vn.y = an.y + b1v.y; vn.z = an.z + b1v.z; vn.w = an.w + b1v.w;
    *(float4*)(nout + (size_t)d * D1 + 4 * li) = vn;
  }
}

// ---------------- layer-2 fused (xlr2 [NN][32]: cols 0-15 xl, 16-31 xr) ----------------
__global__ __launch_bounds__(256) void k_fused2(
    const float* __restrict__ xlr, const float* __restrict__ att,
    const int* __restrict__ sperm, const int* __restrict__ eperm,
    const int* __restrict__ starts, const int* __restrict__ counts,
    const int* __restrict__ kptr, const float* __restrict__ bias,
    float* __restrict__ out0, float* __restrict__ out1) {
  __shared__ float sc[4][CAP];
  int w = threadIdx.x >> 6;
  int l = threadIdx.x & 63;
  int d = blockIdx.x * 4 + w;
  if (d >= NN) return;
  int st = starts[d];
  int deg = counts[d];
  if (deg > CAP) deg = CAP;
  int k = kptr[0];

  int srcreg = 0, idreg = 0x7fffffff;
  if (l < deg) { srcreg = sperm[st + l]; idreg = eperm[st + l]; }

  int g = l >> 4, li = l & 15;
  float xrv = xlr[(size_t)d * 32 + 16 + li];
  float attv = att[li];
  float bv2 = bias[li];

  // ---- scoring: 8 rows in flight ----
  for (int q = 0; q < deg; q += 8) {
    int r0 = q + g, r1 = q + 4 + g;
    int s0 = __shfl(srcreg, r0), s1 = __shfl(srcreg, r1);
    float x0 = (r0 < deg) ? xlr[(size_t)s0 * 32 + li] : 0.f;
    float x1 = (r1 < deg) ? xlr[(size_t)s1 * 32 + li] : 0.f;
    float a0 = x0 + xrv, a1 = x1 + xrv;
    float p0 = fmaxf(a0, NEG * a0) * attv;
    float p1 = fmaxf(a1, NEG * a1) * attv;
#pragma unroll
    for (int o = 1; o <= 8; o <<= 1) {
      p0 += __shfl_xor(p0, o, 64);
      p1 += __shfl_xor(p1, o, 64);
    }
    if (li == 0) {
      if (r0 < deg) sc[w][r0] = p0;
      if (r1 < deg) sc[w][r1] = p1;
    }
  }

  // ---- top-k + dual softmax: lane = edge ----
  float sv = (l < deg) ? sc[w][l] : NINF;
  int si = idreg;
  int rank = 0;
  for (int p = 0; p < deg; p++) {
    float bv = __shfl(sv, p);
    int bi = __shfl(si, p);
    rank += lex_gt(bv, bi, sv, si);
  }
  bool kept = (l < deg) && (rank < k);
  float mk = sv, mn = kept ? NINF : sv;
#pragma unroll
  for (int o = 1; o <= 32; o <<= 1) {
    mk = fmaxf(mk, __shfl_xor(mk, o, 64));
    mn = fmaxf(mn, __shfl_xor(mn, o, 64));
  }
  float ek = kept ? __expf(sv - mk) : 0.f;
  float en = ((l < deg) && !kept) ? __expf(sv - mn) : 0.f;
  float sk = ek, sn = en;
#pragma unroll
  for (int o = 1; o <= 32; o <<= 1) {
    sk += __shfl_xor(sk, o, 64);
    sn += __shfl_xor(sn, o, 64);
  }
  if (l < deg) sc[w][l] = kept ? ek / (sk + 1e-16f) : -(en / (sn + 1e-16f));

  // ---- aggregation (branchless) ----
  float ao = 0.f, an = 0.f;
  for (int q = 0; q < deg; q += 4) {
    int r = q + g;
    int s = __shfl(srcreg, r);
    if (r < deg) {
      float wv = sc[w][r];
      float pw = fmaxf(wv, 0.f), nw = pw - wv;
      float xv = xlr[(size_t)s * 32 + li];
      ao += pw * xv; an += nw * xv;
    }
  }
  ao += __shfl_xor(ao, 16, 64); ao += __shfl_xor(ao, 32, 64);
  an += __shfl_xor(an, 16, 64); an += __shfl_xor(an, 32, 64);
  float vo = ao + bv2, vn = an + bv2;
  float mo = vo, mv = vn;
#pragma unroll
  for (int o = 1; o <= 8; o <<= 1) {
    mo = fmaxf(mo, __shfl_xor(mo, o, 64));
    mv = fmaxf(mv, __shfl_xor(mv, o, 64));
  }
  float eo = __expf(vo - mo), ev = __expf(vn - mv);
#pragma unroll
  for (int o = 1; o <= 8; o <<= 1) {
    eo += __shfl_xor(eo, o, 64);
    ev += __shfl_xor(ev, o, 64);
  }
  if (g == 0) out0[(size_t)d * NCLS + li] = vo - (mo + logf(eo));
  if (g == 1) out1[(size_t)d * NCLS + li] = vn - (mv + logf(ev));
}

// ---------------- row log_softmax over 16 (n1 only) ----------------
__global__ void k_lsm(const float* __restrict__ in, float* __restrict__ out) {
  int r = blockIdx.x * 256 + threadIdx.x;
  if (r >= NN) return;
  const float4* p = (const float4*)(in + (size_t)r * NCLS);
  float4 a = p[0], b = p[1], c = p[2], d4 = p[3];
  float vals[16] = {a.x, a.y, a.z, a.w, b.x, b.y, b.z, b.w,
                    c.x, c.y, c.z, c.w, d4.x, d4.y, d4.z, d4.w};
  float m = vals[0];
#pragma unroll
  for (int i = 1; i < 16; i++) m = fmaxf(m, vals[i]);
  float s = 0.f;
#pragma unroll
  for (int i = 0; i < 16; i++) s += expf(vals[i] - m);
  float l = m + logf(s);
  float* op = out + (size_t)r * NCLS;
#pragma unroll
  for (int i = 0; i < 16; i++) op[i] = vals[i] - l;
}

extern "C" void kernel_launch(void* const* d_in, const int* in_sizes, int n_in,
                              void* d_out, int out_size, void* d_ws, size_t ws_size,
                              hipStream_t stream) {
  (void)in_sizes; (void)n_in; (void)out_size; (void)ws_size;
  const float* x    = (const float*)d_in[0];
  const int*   ei   = (const int*)d_in[1];
  const int*   kptr = (const int*)d_in[2];
  const float* Wl1  = (const float*)d_in[3];
  const float* Wr1  = (const float*)d_in[4];
  const float* att1 = (const float*)d_in[5];
  const float* b1   = (const float*)d_in[6];
  const float* Wl2  = (const float*)d_in[7];
  const float* Wr2  = (const float*)d_in[8];
  const float* att2 = (const float*)d_in[9];
  const float* b2   = (const float*)d_in[10];
  const float* l1w  = (const float*)d_in[11];
  const float* l1b  = (const float*)d_in[12];
  const float* l2w  = (const float*)d_in[13];
  const float* l2b  = (const float*)d_in[14];
  const int* srcv = ei;
  const int* dstv = ei + NE;

  char* wp = (char*)d_ws;
  auto alloc = [&](size_t n) { char* p = wp; wp += (n + 255) & ~(size_t)255; return p; };
  float* xlr1   = (float*)alloc((size_t)NN * 256 * 4);  // [NN][256] xl|xr
  float* hbuf   = (float*)alloc((size_t)NN * D1 * 4);   // h = elu(out1+b1)
  float* noise1 = (float*)alloc((size_t)NN * D1 * 4);
  float* t1     = (float*)alloc((size_t)NN * D1 * 4);   // mlp hidden
  float* xlr2   = (float*)alloc((size_t)NN * 32 * 4);   // [NN][32] xl2|xr2
  float* n1buf  = (float*)alloc((size_t)NN * NCLS * 4);
  int* counts = (int*)alloc((size_t)NN * 4);
  int* starts = (int*)alloc((size_t)NN * 4);
  int* cursor = (int*)alloc((size_t)NN * 4);
  int* eperm  = (int*)alloc((size_t)NE * 4);
  int* sperm  = (int*)alloc((size_t)NE * 4);
  int* bsum   = (int*)alloc((size_t)NSB * 4);
  int* boff   = (int*)alloc((size_t)NSB * 4);

  // CSR build (by dst) — parallel 3-phase scan
  hipMemsetAsync(counts, 0, (size_t)NN * 4, stream);
  k_count<<<(NE + 255) / 256, 256, 0, stream>>>(dstv, counts);
  k_scanA<<<NSB, 256, 0, stream>>>(counts, bsum);
  k_scanB<<<1, 256, 0, stream>>>(bsum, boff);
  k_scanC<<<NSB, 256, 0, stream>>>(counts, boff, starts, cursor);
  k_scatter<<<(NE + 255) / 256, 256, 0, stream>>>(srcv, dstv, cursor, eperm, sperm);

  // Layer 1 node transforms: x @ [Wl1|Wr1] -> xlr1 [NN][256]
  k_gemm2<64, 128, 32, 4, 8, 0><<<dim3(2, (NN + 63) / 64), 256, 0, stream>>>(
      x, Wl1, Wr1, 128, 128, 128, nullptr, xlr1, NN, 256, FIN);

  // Layer 1 fused edge pipeline
  k_fused1<<<(NN + 3) / 4, 256, 0, stream>>>(xlr1, att1, sperm, eperm,
                                             starts, counts, kptr, b1, hbuf, noise1);

  // MLP on noise1: elu(noise1@l1w+l1b) -> t1; t1@l2w+l2b -> n1buf
  k_gemm2<64, 128, 32, 4, 8, 1><<<dim3(1, (NN + 63) / 64), 256, 0, stream>>>(
      noise1, l1w, l1w, 128, 128, 128, l1b, t1, NN, 128, 128);
  k_gemm2<256, 16, 32, 4, 4, 0><<<dim3(1, (NN + 255) / 256), 256, 0, stream>>>(
      t1, l2w, l2w, 16, 16, 16, l2b, n1buf, NN, NCLS, 128);

  // Layer 2 node transforms: h @ [Wl2|Wr2] -> xlr2 [NN][32]
  k_gemm2<128, 32, 32, 4, 4, 0><<<dim3(1, (NN + 127) / 128), 256, 0, stream>>>(
      hbuf, Wl2, Wr2, 16, 16, 16, nullptr, xlr2, NN, 32, D1);

  // Layer 2 fused edge pipeline (+log_softmax epilogue) -> final outputs
  float* o = (float*)d_out;
  k_fused2<<<(NN + 3) / 4, 256, 0, stream>>>(xlr2, att2, sperm, eperm, starts,
                                             counts, kptr, b2, o,
                                             o + (size_t)2 * NN * NCLS);

  // n1 log_softmax
  k_lsm<<<(NN + 255) / 256, 256, 0, stream>>>(n1buf, o + (size_t)NN * NCLS);
}